// Round 1
// baseline (40.377 us; speedup 1.0000x reference)
//
#include <hip/hip_runtime.h>

// 4-level db4 wavedec, mode='symmetric', faithful to the JAX/pywt reference.
// x: [B=64, L=4096, C=32] f32.  Out (flat concat): cA4,cD4,cD3,cD2,cD1 each [B,C,len].
// lens: L0=4096 -> 2051 -> 1029 -> 518 -> 262.

#define NC 32
#define NB 64
#define TILE_I 64
#define IN_TILE (2 * TILE_I + 6)  // j range [2*i0-6, 2*i0+127] => 134 samples

__device__ __forceinline__ int sym_idx(int t, int L) {
    if (t < 0) t = -1 - t;
    if (t >= L) t = 2 * L - 1 - t;
    return t;
}

// in : channel-interleaved [NB, Lin, NC]
// caOut: if !CA_TRANSPOSED -> interleaved [NB, Lout, NC] (ws); else -> [NB, NC, Lout] (d_out chunk)
// cdOut: [NB, NC, Lout] (d_out chunk)
template <bool CA_TRANSPOSED>
__global__ __launch_bounds__(256) void dwt_step_kernel(
    const float* __restrict__ in, float* __restrict__ caOut,
    float* __restrict__ cdOut, int Lin, int Lout) {
    __shared__ float s_in[IN_TILE][NC];
    __shared__ float s_cd[NC][TILE_I + 1];
    __shared__ float s_ca[NC][TILE_I + 1];

    const int b = blockIdx.y;
    const int i0 = blockIdx.x * TILE_I;
    const int tid = threadIdx.x;

    // ---- stage input tile (float4 across channels, coalesced) ----
    const int tbase = 2 * i0 - 6;
    const float* inB = in + (size_t)b * Lin * NC;
    for (int q = tid; q < IN_TILE * (NC / 4); q += 256) {
        const int jj = q >> 3;          // sample within tile
        const int c4 = (q & 7) << 2;    // channel*4
        const int t = sym_idx(tbase + jj, Lin);
        const float4 v = *reinterpret_cast<const float4*>(inB + (size_t)t * NC + c4);
        *reinterpret_cast<float4*>(&s_in[jj][c4]) = v;
    }
    __syncthreads();

    // db4 correlation kernels (dec_lo reversed = _H; dec_hi reversed)
    constexpr float FLO[8] = {
        0.23037781330885523f,  0.7148465705525415f,  0.6308807679295904f,
        -0.02798376941698385f, -0.18703481171888114f, 0.030841381835986965f,
        0.032883011666982945f, -0.010597401784997278f};
    constexpr float FHI[8] = {
        -0.010597401784997278f, -0.032883011666982945f, 0.030841381835986965f,
        0.18703481171888114f,  -0.02798376941698385f,  -0.6308807679295904f,
        0.7148465705525415f,   -0.23037781330885523f};

    const int c = tid & 31;
    const int r0 = tid >> 5;  // 0..7

#pragma unroll
    for (int r = 0; r < 8; ++r) {
        const int ii = r0 * 8 + r;  // 0..63
        const int i = i0 + ii;
        float a = 0.f, d = 0.f;
#pragma unroll
        for (int k = 0; k < 8; ++k) {
            const float v = s_in[2 * ii + k][c];
            a = fmaf(FLO[k], v, a);
            d = fmaf(FHI[k], v, d);
        }
        if (i < Lout) {
            if (!CA_TRANSPOSED) {
                caOut[((size_t)b * Lout + i) * NC + c] = a;  // interleaved, coalesced
            } else {
                s_ca[c][ii] = a;
            }
            s_cd[c][ii] = d;
        }
    }
    __syncthreads();

    // ---- transposed write-out of cD (and cA at final level) ----
    const int nvalid = min(TILE_I, Lout - i0);
    for (int e = tid; e < NC * TILE_I; e += 256) {
        const int c2 = e >> 6;
        const int ii = e & 63;
        if (ii < nvalid) {
            const size_t off = ((size_t)b * NC + c2) * Lout + i0 + ii;
            cdOut[off] = s_cd[c2][ii];
            if (CA_TRANSPOSED) caOut[off] = s_ca[c2][ii];
        }
    }
}

extern "C" void kernel_launch(void* const* d_in, const int* in_sizes, int n_in,
                              void* d_out, int out_size, void* d_ws, size_t ws_size,
                              hipStream_t stream) {
    const float* x = (const float*)d_in[0];
    float* out = (float*)d_out;
    float* ws = (float*)d_ws;

    const int L0 = 4096, L1 = 2051, L2 = 1029, L3 = 518, L4 = 262;
    const size_t S = (size_t)NB * NC;  // 2048 signals

    // d_out offsets (flat concat: cA4, cD4, cD3, cD2, cD1)
    const size_t off_cA4 = 0;
    const size_t off_cD4 = off_cA4 + S * L4;
    const size_t off_cD3 = off_cD4 + S * L4;
    const size_t off_cD2 = off_cD3 + S * L3;
    const size_t off_cD1 = off_cD2 + S * L2;

    // ws layout (channel-interleaved cA buffers)
    float* cA1 = ws;                   // NB*L1*NC
    float* cA2 = ws + (size_t)NB * L1 * NC;  // NB*L2*NC
    float* cA3 = ws;                   // reuse cA1's space (level 3 reads cA2 only)

    dim3 blk(256);
    dwt_step_kernel<false><<<dim3((L1 + TILE_I - 1) / TILE_I, NB), blk, 0, stream>>>(
        x, cA1, out + off_cD1, L0, L1);
    dwt_step_kernel<false><<<dim3((L2 + TILE_I - 1) / TILE_I, NB), blk, 0, stream>>>(
        cA1, cA2, out + off_cD2, L1, L2);
    dwt_step_kernel<false><<<dim3((L3 + TILE_I - 1) / TILE_I, NB), blk, 0, stream>>>(
        cA2, cA3, out + off_cD3, L2, L3);
    dwt_step_kernel<true><<<dim3((L4 + TILE_I - 1) / TILE_I, NB), blk, 0, stream>>>(
        cA3, out + off_cA4, out + off_cD4, L3, L4);
}

// Round 2
// 32.559 us; speedup vs baseline: 1.2401x; 1.2401x over previous
//
#include <hip/hip_runtime.h>

// Fully-fused 4-level db4 wavedec ('symmetric'), faithful to the JAX/pywt reference.
// x: [B=64, L=4096, C=32] f32.  Out flat concat: cA4,cD4,cD3,cD2,cD1 each [B,C,len].
// lens: 4096 -> 2051 -> 1029 -> 518 -> 262.
// One block = (batch b, channel-group of 8, tile of 33 cA4 outputs). All levels in LDS.

#define NCH 8

__device__ __forceinline__ int sym_idx(int t, int L) {
    if (t < 0) t = -1 - t;
    if (t >= L) t = 2 * L - 1 - t;
    return t;
}

__device__ __forceinline__ void level_step(
    const float* __restrict__ src, int src_base, int srcL,
    float* __restrict__ dst, int dst_base,
    int lo, int hi,
    float* __restrict__ cdRow, int ownLo, int ownHi,
    float* __restrict__ caRow,  // non-null only at level 4
    int c, int slot) {
    // db4 correlation kernels (dec_lo reversed = _H; dec_hi reversed).
    constexpr float FLO[8] = {
        0.23037781330885523f,  0.7148465705525415f,  0.6308807679295904f,
        -0.02798376941698385f, -0.18703481171888114f, 0.030841381835986965f,
        0.032883011666982945f, -0.010597401784997278f};
    constexpr float FHI[8] = {
        -0.010597401784997278f, -0.032883011666982945f, 0.030841381835986965f,
        0.18703481171888114f,  -0.02798376941698385f,  -0.6308807679295904f,
        0.7148465705525415f,   -0.23037781330885523f};

    for (int i = lo + slot; i < hi; i += 32) {
        float a = 0.f, d = 0.f;
#pragma unroll
        for (int k = 0; k < 8; ++k) {
            int t = sym_idx(2 * i - 6 + k, srcL);
            const float v = src[(t - src_base) * NCH + c];
            a = fmaf(FLO[k], v, a);
            d = fmaf(FHI[k], v, d);
        }
        if (dst) dst[(i - dst_base) * NCH + c] = a;
        if (caRow) caRow[i] = a;
        if (i >= ownLo && i < ownHi) cdRow[i] = d;
    }
}

__global__ __launch_bounds__(256) void fused_dwt_kernel(
    const float* __restrict__ x, float* __restrict__ out) {
    // XCD swizzle: 2048 blocks = 8 XCDs x 256; give each XCD a contiguous chunk
    // so the 4 channel-group siblings (consecutive work ids) share one L2.
    const int bid = blockIdx.x;
    const int work = (bid & 7) * 256 + (bid >> 3);
    const int cg = work & 3;          // channel group 0..3
    const int tile = (work >> 2) & 7; // cA4 tile 0..7
    const int b = work >> 5;          // batch 0..63

    const int tid = threadIdx.x;
    const int c = tid & 7;
    const int slot = tid >> 3;  // 0..31
    const int c0 = cg * 8;

    const int L0 = 4096, L1 = 2051, L2 = 1029, L3 = 518, L4 = 262;

    // computed (halo) ranges per level, clamped
    const int lo4 = tile * 33, hi4 = min(L4, lo4 + 33);
    const int lo3 = max(0, 2 * lo4 - 6), hi3 = min(L3, 2 * hi4);
    const int lo2 = max(0, 2 * lo3 - 6), hi2 = min(L2, 2 * hi3);
    const int lo1 = max(0, 2 * lo2 - 6), hi1 = min(L1, 2 * hi2);
    const int lox = max(0, 2 * lo1 - 6), hix = min(L0, 2 * hi1);

    __shared__ float bx[618 * NCH];
    __shared__ float b1[306 * NCH];
    __shared__ float b2[150 * NCH];
    __shared__ float b3[72 * NCH];

    // ---- stage x tile: rows [lox, hix) x 8 channels, float4 loads ----
    const float* xb = x + (size_t)b * L0 * 32 + c0;
    const int nx = hix - lox;
    for (int q = tid; q < nx * 2; q += 256) {
        const int jj = q >> 1;
        const int h = (q & 1) * 4;
        const float4 v = *reinterpret_cast<const float4*>(xb + (size_t)(lox + jj) * 32 + h);
        *reinterpret_cast<float4*>(&bx[jj * NCH + h]) = v;
    }
    __syncthreads();

    // d_out chunk offsets
    const size_t S = 2048;
    float* outCA4 = out;
    float* outCD4 = out + S * (size_t)L4;
    float* outCD3 = out + 2 * S * (size_t)L4;
    float* outCD2 = out + 2 * S * (size_t)L4 + S * (size_t)L3;
    float* outCD1 = out + 2 * S * (size_t)L4 + S * (size_t)L3 + S * (size_t)L2;

    const size_t sig = (size_t)b * 32 + c0 + c;

    // owned (exclusive) detail ranges per tile
    const int o1lo = tile * 264, o1hi = min(L1, o1lo + 264);
    const int o2lo = tile * 132, o2hi = min(L2, o2lo + 132);
    const int o3lo = tile * 66, o3hi = min(L3, o3lo + 66);

    level_step(bx, lox, L0, b1, lo1, lo1, hi1,
               outCD1 + sig * L1, o1lo, o1hi, nullptr, c, slot);
    __syncthreads();
    level_step(b1, lo1, L1, b2, lo2, lo2, hi2,
               outCD2 + sig * L2, o2lo, o2hi, nullptr, c, slot);
    __syncthreads();
    level_step(b2, lo2, L2, b3, lo3, lo3, hi3,
               outCD3 + sig * L3, o3lo, o3hi, nullptr, c, slot);
    __syncthreads();
    level_step(b3, lo3, L3, nullptr, 0, lo4, hi4,
               outCD4 + sig * L4, lo4, hi4, outCA4 + sig * L4, c, slot);
}

extern "C" void kernel_launch(void* const* d_in, const int* in_sizes, int n_in,
                              void* d_out, int out_size, void* d_ws, size_t ws_size,
                              hipStream_t stream) {
    const float* x = (const float*)d_in[0];
    float* out = (float*)d_out;
    fused_dwt_kernel<<<dim3(2048), dim3(256), 0, stream>>>(x, out);
}